// Round 15
// baseline (216.990 us; speedup 1.0000x reference)
//
#include <hip/hip_runtime.h>
#include <math.h>

typedef unsigned short u16;
typedef __attribute__((ext_vector_type(8))) short bf8;          // 8 x bf16 (4 VGPR) MFMA frag
typedef __attribute__((ext_vector_type(4))) float f4;           // 16x16 MFMA acc
typedef __attribute__((ext_vector_type(16))) float f32x16;      // 32x32 MFMA acc
typedef __attribute__((ext_vector_type(4))) unsigned int u32x4; // 16B staging
typedef __attribute__((ext_vector_type(2))) unsigned int u32x2;
typedef __attribute__((ext_vector_type(4))) unsigned short u16x4;
typedef __attribute__((ext_vector_type(8))) unsigned short u16x8;

__device__ __forceinline__ float bf2f(u16 a){
  unsigned u = ((unsigned)a) << 16;
  float f; __builtin_memcpy(&f, &u, 4);
  return f;
}
__device__ __forceinline__ u16 f2bf(float f){
  unsigned u; __builtin_memcpy(&u, &f, 4);
  u += 0x7fffu + ((u >> 16) & 1u);   // RNE
  return (u16)(u >> 16);
}
// v_cvt_pk_bf16_f32: lo16 = bf16(a), hi16 = bf16(b)
__device__ __forceinline__ unsigned cvtpk(float a, float b){
  unsigned r;
  asm("v_cvt_pk_bf16_f32 %0, %1, %2" : "=v"(r) : "v"(a), "v"(b));
  return r;
}
// v_permlane32_swap_b32
__device__ __forceinline__ void plswap(unsigned &a, unsigned &b){
  asm("v_permlane32_swap_b32 %0, %1" : "+v"(a), "+v"(b));
}
// async global->LDS 16B (dest = wave-uniform base + lane*16)
__device__ __forceinline__ void gload16(const u16* g, u16* l){
  __builtin_amdgcn_global_load_lds((const __attribute__((address_space(1))) void*)g,
                                   (__attribute__((address_space(3))) void*)l, 16, 0, 0);
}
// bijective XCD-chunked block swizzle (m204)
__device__ __forceinline__ int xcd_swizzle(int orig, int nwg){
  const int qq = nwg >> 3, rr = nwg & 7;
  const int xcd = orig & 7, loc = orig >> 3;
  return (xcd < rr ? xcd * (qq + 1) : rr * (qq + 1) + (xcd - rr) * qq) + loc;
}
// exact-enough GELU: x * sigmoid(2 * 0.79788456*(x + 0.044715 x^3))
__device__ __forceinline__ float gelu_f(float v){
  const float vc = fminf(v, 10.f);
  const float z  = vc * (1.f + 0.044715f * vc * vc);   // vc + 0.044715 vc^3
  const float e  = __builtin_amdgcn_exp2f(2.302208499f * z); // 2*0.79788456*log2e
  return v * e * __builtin_amdgcn_rcpf(e + 1.f);
}

// ---------------- fused transpose+cast of all 8 weights ---------------------
__global__ void k_transpose_all(
    const float* __restrict__ Wq, const float* __restrict__ Wk,
    const float* __restrict__ Wv, const float* __restrict__ Wo,
    const float* __restrict__ Win, const float* __restrict__ Wmo,
    const float* __restrict__ W1, const float* __restrict__ W2,
    u16* __restrict__ WqT, u16* __restrict__ WkT, u16* __restrict__ WvT,
    u16* __restrict__ WoT, u16* __restrict__ WinT, u16* __restrict__ WmoT,
    u16* __restrict__ W1T, u16* __restrict__ W2T)
{
  __shared__ float tile[32][33];
  const int tid = blockIdx.x;
  const float* in; u16* out; int R, C, lo;
  if (tid < 1280){
    if (tid < 256)       { in = Wq;  out = WqT;  R = 512; C = 512;  lo = 0; }
    else if (tid < 640)  { in = Wk;  out = WkT;  R = 768; C = 512;  lo = 256; }
    else if (tid < 1024) { in = Wv;  out = WvT;  R = 768; C = 512;  lo = 640; }
    else                 { in = Wo;  out = WoT;  R = 512; C = 512;  lo = 1024; }
  } else {
    if (tid < 2048)      { in = Win; out = WinT; R = 512; C = 1536; lo = 1280; }
    else if (tid < 2304) { in = Wmo; out = WmoT; R = 512; C = 512;  lo = 2048; }
    else if (tid < 3328) { in = W1;  out = W1T;  R = 512; C = 2048; lo = 2304; }
    else                 { in = W2;  out = W2T;  R = 2048; C = 512; lo = 3328; }
  }
  const int local = tid - lo;
  const int tpx = C >> 5;
  const int bx = (local % tpx) * 32, by = (local / tpx) * 32;
  const int tx = threadIdx.x, ty = threadIdx.y;   // (32,8)
#pragma unroll
  for (int i = 0; i < 4; i++)
    tile[ty + i*8][tx] = in[(size_t)(by + ty + i*8) * C + bx + tx];
  __syncthreads();
#pragma unroll
  for (int i = 0; i < 4; i++)
    out[(size_t)(bx + ty + i*8) * R + by + tx] = f2bf(tile[tx][ty + i*8]);
}

// ---------------- LayerNorm (f32 in -> bf16 out) ----------------------------
__device__ __forceinline__ void ln_row_f32(
    const float* __restrict__ r, const float* __restrict__ gam,
    const float* __restrict__ bet, u16* __restrict__ outb, int D, int t)
{
  const int nv = D >> 8;                 // 2 (D=512) or 3 (D=768)
  float v[3] = {0.f, 0.f, 0.f};
  float s = 0.f, s2 = 0.f;
#pragma unroll
  for (int i = 0; i < 3; i++){
    if (i < nv){ float xx = r[t + i*256]; v[i] = xx; s += xx; s2 += xx*xx; }
  }
#pragma unroll
  for (int m = 32; m; m >>= 1){ s += __shfl_xor(s, m); s2 += __shfl_xor(s2, m); }
  __shared__ float rs[4], rq[4];
  const int wave = t >> 6;
  if ((t & 63) == 0){ rs[wave] = s; rq[wave] = s2; }
  __syncthreads();
  s  = rs[0] + rs[1] + rs[2] + rs[3];
  s2 = rq[0] + rq[1] + rq[2] + rq[3];
  const float mean = s / (float)D;
  const float var  = s2 / (float)D - mean * mean;
  const float rstd = rsqrtf(var + 1e-5f);
#pragma unroll
  for (int i = 0; i < 3; i++){
    if (i < nv){
      const int c = t + i*256;
      outb[c] = f2bf((v[i] - mean) * rstd * gam[c] + bet[c]);
    }
  }
}

// fused LN1 (x, D=512) + LN2 (y, D=768), bf16 outputs
__global__ __launch_bounds__(256) void k_layernorm12(
    const float* __restrict__ x, const float* __restrict__ y,
    const float* __restrict__ g1, const float* __restrict__ b1,
    const float* __restrict__ g2, const float* __restrict__ b2,
    u16* __restrict__ xnB, u16* __restrict__ ynB)
{
  const int row = blockIdx.x;
  if (row < 8192){
    ln_row_f32(x + (size_t)row * 512, g1, b1, xnB + (size_t)row * 512, 512, threadIdx.x);
  } else {
    const int r2 = row - 8192;
    ln_row_f32(y + (size_t)r2 * 768, g2, b2, ynB + (size_t)r2 * 768, 768, threadIdx.x);
  }
}

// LayerNorm bf16 in -> bf16 out, D=512 fixed
__global__ __launch_bounds__(256) void k_layernorm_b(
    const u16* __restrict__ in, const float* __restrict__ gam,
    const float* __restrict__ bet, u16* __restrict__ outb)
{
  const int row = blockIdx.x, t = threadIdx.x;
  const u16* r = in + (size_t)row * 512;
  const float v0 = bf2f(r[t]);
  const float v1 = bf2f(r[t + 256]);
  float s = v0 + v1, s2 = v0*v0 + v1*v1;
#pragma unroll
  for (int m = 32; m; m >>= 1){ s += __shfl_xor(s, m); s2 += __shfl_xor(s2, m); }
  __shared__ float rs[4], rq[4];
  const int wave = t >> 6;
  if ((t & 63) == 0){ rs[wave] = s; rq[wave] = s2; }
  __syncthreads();
  s  = rs[0] + rs[1] + rs[2] + rs[3];
  s2 = rq[0] + rq[1] + rq[2] + rq[3];
  const float mean = s * (1.f / 512.f);
  const float var  = s2 * (1.f / 512.f) - mean * mean;
  const float rstd = rsqrtf(var + 1e-5f);
  u16* o = outb + (size_t)row * 512;
  o[t]       = f2bf((v0 - mean) * rstd * gam[t] + bet[t]);
  o[t + 256] = f2bf((v1 - mean) * rstd * gam[t + 256] + bet[t + 256]);
}

// ---------------- bf16 MFMA GEMM (m97 single-buffer, high co-residency) -----
// res input is bf16. OUTM: 0 = f32 out (W2), 1 = bf16 out,
// 2 = bf16 transposed [b*512+n][2048], 3 = fused k|v (n<512 rows | transposed)
// QSC: scale output by 0.125*log2(e) (q-projection feeds exp2-based softmax)
template<int TM, int TN, bool BIAS, bool RES, bool GELU_ACT, int OUTM, bool QSC = false>
__global__ __launch_bounds__(256, 4) void k_gemm(
    const u16* __restrict__ A, const u16* __restrict__ BT,
    const float* __restrict__ bias, const u16* __restrict__ res,
    float* __restrict__ outf, u16* __restrict__ outb, u16* __restrict__ outb2,
    int M, int N, int K)
{
  constexpr int MF = TM / 32;          // 16-row frags per wave (m)
  constexpr int NF = TN / 32;          // 16-col frags per wave (n)
  constexpr int WM = TM / 2;           // wave m-span
  constexpr int WN = TN / 2;           // wave n-span
  __shared__ u16 Sb[(TM + TN) * 64];   // single buffer: A rows then B rows
  const int t = threadIdx.x;
  const int gx = gridDim.x;
  const int swz = xcd_swizzle(blockIdx.y * gx + blockIdx.x, gx * gridDim.y);
  const int m0 = (swz / gx) * TM, n0 = (swz % gx) * TN;
  const int wave = t >> 6, lane = t & 63;
  const int wm = wave >> 1, wn = wave & 1;
  const int l15 = lane & 15, lg = lane >> 4;
  const u16* Ag = A + (size_t)m0 * K;
  const u16* Bg = BT + (size_t)n0 * K;

  const int lrow = lane >> 3;                       // row within 8-row slice
  const int csrc = (((lane & 7) ^ lrow) << 3);      // swizzled col (elements)
  const u16* Agl = Ag + (size_t)lrow * K + csrc;
  const u16* Bgl = Bg + (size_t)lrow * K + csrc;

  f4 acc[MF][NF];
#pragma unroll
  for (int i = 0; i < MF; i++)
#pragma unroll
    for (int j = 0; j < NF; j++) acc[i][j] = (f4){0.f, 0.f, 0.f, 0.f};

  const int nK = K >> 6;
  // prologue: stage tile 0
#pragma unroll
  for (int i = 0; i < TM/32; i++){
    const int rb = (i*4 + wave) * 8;
    gload16(Agl + (size_t)rb * K, &Sb[rb * 64]);
  }
#pragma unroll
  for (int i = 0; i < TN/32; i++){
    const int rb = (i*4 + wave) * 8;
    gload16(Bgl + (size_t)rb * K, &Sb[(TM + rb) * 64]);
  }
  asm volatile("s_waitcnt vmcnt(0)" ::: "memory");
  __syncthreads();

  for (int kt = 0;; kt++){
    const char* As = (const char*)&Sb[0];
    const char* Bs = (const char*)&Sb[TM * 64];
#pragma unroll
    for (int kc = 0; kc < 2; kc++){
      bf8 af[MF], bfr[NF];
      const int kb = kc*64 + lg*16;                     // byte offset in row
#pragma unroll
      for (int mf = 0; mf < MF; mf++){
        const int row = wm*WM + mf*16 + l15;
        af[mf] = *(const bf8*)(As + row*128 + (kb ^ ((row & 7) << 4)));
      }
#pragma unroll
      for (int nf = 0; nf < NF; nf++){
        const int row = wn*WN + nf*16 + l15;
        bfr[nf] = *(const bf8*)(Bs + row*128 + (kb ^ ((row & 7) << 4)));
      }
#pragma unroll
      for (int mf = 0; mf < MF; mf++)
#pragma unroll
        for (int nf = 0; nf < NF; nf++)
          acc[mf][nf] = __builtin_amdgcn_mfma_f32_16x16x32_bf16(af[mf], bfr[nf], acc[mf][nf], 0, 0, 0);
    }
    if (kt + 1 == nK) break;
    __syncthreads();                       // all reads of Sb done
    const int ko = (kt + 1) << 6;
#pragma unroll
    for (int i = 0; i < TM/32; i++){
      const int rb = (i*4 + wave) * 8;
      gload16(Agl + (size_t)rb * K + ko, &Sb[rb * 64]);
    }
#pragma unroll
    for (int i = 0; i < TN/32; i++){
      const int rb = (i*4 + wave) * 8;
      gload16(Bgl + (size_t)rb * K + ko, &Sb[(TM + rb) * 64]);
    }
    asm volatile("s_waitcnt vmcnt(0)" ::: "memory");
    __syncthreads();                       // staged & visible
  }
  // epilogue
#pragma unroll
  for (int mf = 0; mf < MF; mf++){
#pragma unroll
    for (int nf = 0; nf < NF; nf++){
      const int colg = n0 + wn*WN + nf*16 + l15;
      const int rowg = m0 + wm*WM + mf*16 + lg*4;
      const float bv = BIAS ? bias[colg] : 0.f;
      float vv[4];
#pragma unroll
      for (int j = 0; j < 4; j++){
        float v = acc[mf][nf][j] + bv;
        if (RES) v += bf2f(res[(size_t)(rowg + j) * N + colg]);
        if (GELU_ACT) v = gelu_f(v);
        if (QSC) v *= 0.1803368801f;       // 0.125 * log2(e)
        vv[j] = v;
      }
      if (OUTM == 0){
#pragma unroll
        for (int j = 0; j < 4; j++) outf[(size_t)(rowg + j) * N + colg] = vv[j];
      } else if (OUTM == 1){
#pragma unroll
        for (int j = 0; j < 4; j++) outb[(size_t)(rowg + j) * N + colg] = f2bf(vv[j]);
      } else if (OUTM == 2){
        const int bb = rowg >> 11, ss = rowg & 2047;    // per-batch transpose
        u16x4 pk;
#pragma unroll
        for (int j = 0; j < 4; j++) pk[j] = f2bf(vv[j]);
        *(u16x4*)(outb + ((size_t)(bb*512 + colg)) * 2048 + ss) = pk;
      } else {                                          // OUTM 3: fused k|v
        if (n0 < 512){
#pragma unroll
          for (int j = 0; j < 4; j++) outb[(size_t)(rowg + j) * 512 + colg] = f2bf(vv[j]);
        } else {
          const int bb = rowg >> 11, ss = rowg & 2047;
          u16x4 pk;
#pragma unroll
          for (int j = 0; j < 4; j++) pk[j] = f2bf(vv[j]);
          *(u16x4*)(outb2 + ((size_t)(bb*512 + (colg - 512))) * 2048 + ss) = pk;
        }
      }
    }
  }
}

// ---------------- flash cross-attention v8: KVBLK=128, 48KB LDS -------------
// q pre-scaled by 0.125*log2e -> p = exp2(s). no-max softmax (tiny scores).
// K single-buffered (QK reads fenced by barrier B before restage); V double-
// buffered (staged right after barrier A). Softmax interleaved with PV MFMAs.
__global__ __launch_bounds__(256, 3) void k_flash(
    const u16* __restrict__ q, const u16* __restrict__ k,
    const u16* __restrict__ vt, u16* __restrict__ ctx)
{
  __shared__ u16 Kb[128 * 64];         // [key 128][d 64], 128B rows, swizzled
  __shared__ u16 Vb[2][64 * 128];      // [d 64][key 128], 256B rows, swizzled
  const int t = threadIdx.x;
  const int wave = t >> 6, lane = t & 63;
  const int l31 = lane & 31, hi = lane >> 5;
  const int id = blockIdx.y * 16 + blockIdx.x;   // bh*16 + qb
  const int swz = xcd_swizzle(id, 512);
  const int qb = swz & 15, bh = swz >> 4;
  const int b = bh >> 3, h = bh & 7;
  const int qrow0 = qb*128 + wave*32;

  // Q B-frags: qf[ds] = Q[qrow0+l31][h*64 + ds*16 + hi*8 .. +7]
  bf8 qf[4];
  {
    const u16* qp = q + ((size_t)(b*2048 + qrow0 + l31)) * 512 + h*64 + hi*8;
    qf[0] = *(const bf8*)qp;
    qf[1] = *(const bf8*)(qp + 16);
    qf[2] = *(const bf8*)(qp + 32);
    qf[3] = *(const bf8*)(qp + 48);
  }

  // K staging: 8 rows x 128B per gload, pre-swizzled source col
  const int lrow8 = lane >> 3;
  const int csK = (((lane & 7) ^ lrow8) << 3);
  const u16* kgl = k + ((size_t)(b*2048 + lrow8)) * 512 + h*64 + csK;
  // V staging: 4 rows x 256B per gload; swizzle parity depends on slice
  const int lrow4 = lane >> 4;
  const int csVe = (((lane & 15) ^ lrow4) << 3);        // slice%2==0: row&7 = lrow4
  const int csVo = (((lane & 15) ^ (4 + lrow4)) << 3);  // slice%2==1: row&7 = 4+lrow4
  const u16* vrow = vt + ((size_t)(b*512 + h*64 + lrow4)) * 2048;

  f32x16 o0, o1;
#pragma unroll
  for (int r = 0; r < 16; r++){ o0[r] = 0.f; o1[r] = 0.f; }
  float rl = 0.f;

  // prologue: stage tile 0 (K -> Kb, V -> Vb[0])
#pragma unroll
  for (int i = 0; i < 4; i++){
    const int rb = (i*4 + wave) * 8;
    gload16(kgl + (size_t)rb * 512, &Kb[rb * 64]);
    const int sl = i*4 + wave;
    gload16(vrow + (size_t)(sl*4) * 2048 + ((sl & 1) ? csVo : csVe), &Vb[0][sl * 512]);
  }

  int cur = 0;
  for (int it = 0; it < 16; it++){
    asm volatile("s_waitcnt vmcnt(0)" ::: "memory");
    __syncthreads();                       // A: K = tile it, V[cur] = tile it
    if (it + 1 < 16){                      // stage V(it+1) early (V[cur^1] free)
      const int kt = (it + 1) << 7;
#pragma unroll
      for (int i = 0; i < 4; i++){
        const int sl = i*4 + wave;
        gload16(vrow + (size_t)(sl*4) * 2048 + kt + ((sl & 1) ? csVo : csVe),
                &Vb[cur^1][sl * 512]);
      }
    }
    const char* kbuf = (const char*)Kb;
    const char* vbuf = (const char*)Vb[cur];
    // QK^T swapped, 32x32x16: s{krf} covers keys krf*32..+31 for q=l31
    f32x16 s0, s1, s2, s3;
#pragma unroll
    for (int r = 0; r < 16; r++){ s0[r] = 0.f; s1[r] = 0.f; s2[r] = 0.f; s3[r] = 0.f; }
    __builtin_amdgcn_s_setprio(1);
#pragma unroll
    for (int ds = 0; ds < 4; ds++){
      const int off = ds*32 + hi*16;
      const int r0 = l31, r1 = 32 + l31, r2 = 64 + l31, r3 = 96 + l31;
      const bf8 k0 = *(const bf8*)(kbuf + r0*128 + (off ^ ((r0 & 7) << 4)));
      const bf8 k1 = *(const bf8*)(kbuf + r1*128 + (off ^ ((r1 & 7) << 4)));
      const bf8 k2 = *(const bf8*)(kbuf + r2*128 + (off ^ ((r2 & 7) << 4)));
      const bf8 k3 = *(const bf8*)(kbuf + r3*128 + (off ^ ((r3 & 7) << 4)));
      s0 = __builtin_amdgcn_mfma_f32_32x32x16_bf16(k0, qf[ds], s0, 0, 0, 0);
      s1 = __builtin_amdgcn_mfma_f32_32x32x16_bf16(k1, qf[ds], s1, 0, 0, 0);
      s2 = __builtin_amdgcn_mfma_f32_32x32x16_bf16(k2, qf[ds], s2, 0, 0, 0);
      s3 = __builtin_amdgcn_mfma_f32_32x32x16_bf16(k3, qf[ds], s3, 0, 0, 0);
    }
    __builtin_amdgcn_s_setprio(0);
    __syncthreads();                       // B: all QK reads of Kb done
    if (it + 1 < 16){                      // restage K (async, lands by next A)
      const int kt = (it + 1) << 7;
#pragma unroll
      for (int i = 0; i < 4; i++){
        const int rb = (i*4 + wave) * 8;
        gload16(kgl + (size_t)(kt + rb) * 512, &Kb[rb * 64]);
      }
    }
    // softmax (no max-shift) + pack, interleaved with PV per 32-key sub-tile
    float rsum = 0.f;
#define SMPV(SV, SUB)                                                          \
    {                                                                          \
      float pp[16];                                                            \
      _Pragma("unroll")                                                        \
      for (int r = 0; r < 16; r++) pp[r] = __builtin_amdgcn_exp2f(SV[r]);      \
      _Pragma("unroll")                                                        \
      for (int r = 0; r < 16; r++) rsum += pp[r];                              \
      unsigned w0 = cvtpk(pp[0],  pp[1]),  w1 = cvtpk(pp[2],  pp[3]);          \
      unsigned w2 = cvtpk(pp[4],  pp[5]),  w3 = cvtpk(pp[6],  pp[7]);          \
      unsigned w4 = cvtpk(pp[8],  pp[9]),  w5 = cvtpk(pp[10], pp[11]);         \
      unsigned w6 = cvtpk(pp[12], pp[13]), w7 = cvtpk(pp[14], pp[15]);         \
      plswap(w0, w2); plswap(w1, w3);                                          \
      plswap(w4, w6); plswap(w5, w7);                                          \
      u32x4 t0 = {w0, w1, w2, w3};                                             \
      u32x4 t1 = {w4, w5, w6, w7};                                             \
      bf8 pa0, pa1;                                                            \
      __builtin_memcpy(&pa0, &t0, 16);                                         \
      __builtin_memcpy(&pa1, &t1, 16);                                         \
      const int off0 = SUB*64 + hi*16;                                         \
      const int off1 = SUB*64 + 32 + hi*16;                                    \
      const int r0 = l31, r1 = 32 + l31;                                       \
      const bf8 va0 = *(const bf8*)(vbuf + r0*256 + (off0 ^ ((r0 & 7) << 4))); \
      const bf8 va1 = *(const bf8*)(vbuf + r1*256 + (off0 ^ ((r1 & 7) << 4))); \
      const bf8 vb0 = *(const bf8*)(vbuf + r0*256 + (off1 ^ ((r0 & 7) << 4))); \
      const bf8 vb1 = *(const bf8*)(vbuf + r1*256 + (off1 ^ ((r1 & 7) << 4))); \
      o0 = __builtin_amdgcn_mfma_f32_32x32x16_bf16(pa0, va0, o0, 0, 0, 0);     \
      o1 = __builtin_amdgcn_mfma_f32_32x32x16_bf16(pa0, va1, o1, 0, 0, 0);     \
      o0 = __builtin_amdgcn_mfma_f32_32x32x16_bf16(pa1, vb0, o0, 0, 0, 0);     \
      o1 = __builtin_amdgcn_mfma_f32_32x32x16_bf16(pa1, vb1, o1, 0, 0, 0);     \
    }
    SMPV(s0, 0)
    SMPV(s1, 1)
    SMPV(s2, 2)
    SMPV(s3, 3)
#undef SMPV
    rsum += __shfl_xor(rsum, 32);
    rl += rsum;
    cur ^= 1;
  }
  // epilogue: divide by row sum, write ctx. o reg r: q = (r&3)+8*(r>>2)+4*hi,
  // d = dfrag*32 + l31.
  const float linv = 1.f / rl;             // valid for q = l31
#pragma unroll
  for (int r = 0; r < 16; r++){
    const int crow = (r & 3) + 8*(r >> 2) + 4*hi;
    const float iv = __shfl(linv, crow);
    u16* cp = ctx + ((size_t)(b*2048 + qrow0 + crow)) * 512 + h*64 + l31;
    cp[0]  = f2bf(o0[r] * iv);
    cp[32] = f2bf(o1[r] * iv);
  }
}

// ---------------- tiny MHA (batch_first=False: attends over L=4) ------------
__global__ __launch_bounds__(256) void k_mha_small(const u16* __restrict__ qkv,
                                                   u16* __restrict__ outb)
{
  const int tid = blockIdx.x * 256 + threadIdx.x;  // 65536 threads
  const int n = tid & 2047;
  const int hl = tid >> 11;
  const int h = hl >> 2, l = hl & 3;
  const u16* qp = qkv + ((size_t)l * 2048 + n) * 1536 + h*64;
  float qv[64];
#pragma unroll
  for (int i = 0; i < 8; i++){
    const bf8 c = *(const bf8*)(qp + i*8);
#pragma unroll
    for (int j2 = 0; j2 < 8; j2++) qv[i*8 + j2] = bf2f((u16)c[j2]) * 0.125f;
  }
  float sc[4];
#pragma unroll
  for (int m = 0; m < 4; m++){
    const u16* kp = qkv + ((size_t)m * 2048 + n) * 1536 + 512 + h*64;
    float a = 0.f;
#pragma unroll
    for (int i = 0; i < 8; i++){
      const bf8 c = *(const bf8*)(kp + i*8);
#pragma unroll
      for (int j2 = 0; j2 < 8; j2++) a += qv[i*8 + j2] * bf2f((u16)c[j2]);
    }
    sc[m] = a;
  }
  const float mx = fmaxf(fmaxf(sc[0], sc[1]), fmaxf(sc[2], sc[3]));
  float p[4]; float sum = 0.f;
#pragma unroll
  for (int m = 0; m < 4; m++){ p[m] = __expf(sc[m] - mx); sum += p[m]; }
  const float inv = 1.f / sum;
  float ov[64];
#pragma unroll
  for (int i = 0; i < 64; i++) ov[i] = 0.f;
#pragma unroll
  for (int m = 0; m < 4; m++){
    const float pw = p[m] * inv;
    const u16* vp = qkv + ((size_t)m * 2048 + n) * 1536 + 1024 + h*64;
#pragma unroll
    for (int i = 0; i < 8; i++){
      const bf8 c = *(const bf8*)(vp + i*8);
#pragma unroll
      for (int j2 = 0; j2 < 8; j2++) ov[i*8 + j2] += pw * bf2f((u16)c[j2]);
    }
  }
  u16* op = outb + ((size_t)l * 2048 + n) * 512 + h*64;
#pragma unroll
  for (int i = 0; i < 8; i++){
    u16x8 pk;
#pragma unroll
    for (int j2 = 0; j2 < 8; j2++) pk[j2] = f2bf(ov[i*8 + j2]);
    *(u16x8*)(op + i*8) = pk;
  }
}

// ---------------------------------------------------------------------------
extern "C" void kernel_launch(void* const* d_in, const int* in_sizes, int n_in,
                              void* d_out, int out_size, void* d_ws, size_t ws_size,
                              hipStream_t stream)
{
  (void)in_sizes; (void)n_in; (void)out_size; (void)ws_size;
  const float* x    = (const float*)d_in[0];
  const float* y    = (const float*)d_in[1];
  const float* Wq   = (const float*)d_in[2];
  const float* Wk   = (const float*)d_in[3];
  const float* Wv   = (const float*)d_in[4];
  const float* Wo   = (const float*)d_in[5];
  const float* bo   = (const float*)d_in[6];
  const float* Win  = (const float*)d_in[7];
  const float* bin  = (const float*)d_in[8];
  const float* Wmo  = (const float*)d_in[9];
  const float* bmo  = (const float*)d_in[10];
  const float* ln1g = (const float*)d_in[11];
  const float* ln1b = (const float*)d_in[12];
  const float* ln2g = (const float*)d_in[13];
  const float* ln2b = (const float*)d_in[14];
  const float* ln3g = (const float*)d_in[15];
  const float* ln3b = (const float*)d_in[16];
  const float* ln4g = (const float*)d_in[17];
  const float* ln4b = (const float*)d_in[18];
  const float* W1   = (const float*)d_in[19];
  const float* b1   = (const float*)d_in[20];
  const float* W2   = (const float*)d_in[21];
  const float* b2   = (const float*)d_in[22];

  char* ws = (char*)d_ws;
  const size_t MB = 1024 * 1024;
  // bf16 transposed weights (~8.5 MB); WkT and WvT adjacent -> fused k|v GEMM
  u16* WqT  = (u16*)ws;
  u16* WkT  = WqT  + 512 * 512;
  u16* WvT  = WkT  + 512 * 768;
  u16* WoT  = WvT  + 512 * 768;
  u16* WinT = WoT  + 512 * 512;
  u16* WmoT = WinT + 1536 * 512;
  u16* W1T  = WmoT + 512 * 512;
  u16* W2T  = W1T  + 2048 * 512;
  // all-bf16 activation buffers with lifetime-based aliasing (<=109 MB)
  u16* xnB  = (u16*)(ws +   9 * MB);  // 8MB  LN1 out; res for Wo
  u16* ynB  = (u16*)(ws +  17 * MB);  // 12MB LN2 out
  u16* qB   = (u16*)(ws +  29 * MB);  // 8MB  q (pre-scaled); dead after flash
  u16* kB   = (u16*)(ws +  37 * MB);  // 8MB  k; dead after flash
  u16* vtB  = (u16*)(ws +  45 * MB);  // 8MB  v^T; dead after flash
  u16* ctxB = (u16*)(ws +  53 * MB);  // 8MB  flash out; dead after Wo
  u16* carB = (u16*)(ws +  61 * MB);  // 8MB  ca+xn; dead after LN3
  u16* hB   = (u16*)(ws +  69 * MB);  // 8MB  LN3 out; res for Wmo
  u16* qkvB = (u16*)(ws +  77 * MB);  // 24MB Win out; dead after mha
  u16* saB  = (u16*)(ws + 101 * MB);  // 8MB  mha out
  u16* sarB = qB;                     // sa+h (qB dead)
  u16* h2B  = kB;                     // LN4 out (kB dead)
  u16* t1B  = vtB;                    // 32MB GELU(..) spans 45..77 (all dead)

  k_transpose_all<<<4352, dim3(32, 8), 0, stream>>>(
      Wq, Wk, Wv, Wo, Win, Wmo, W1, W2,
      WqT, WkT, WvT, WoT, WinT, WmoT, W1T, W2T);

  k_layernorm12<<<16384, 256, 0, stream>>>(x, y, ln1g, ln1b, ln2g, ln2b, xnB, ynB);

  // q projection (pre-scaled for exp2 softmax); fused k|v projection
  k_gemm<64,128,false,false,false,1,true><<<dim3(4, 128), 256, 0, stream>>>(xnB, WqT, nullptr, nullptr, nullptr, qB, nullptr, 8192, 512, 512);
  k_gemm<64,128,false,false,false,3><<<dim3(8, 128), 256, 0, stream>>>(ynB, WkT, nullptr, nullptr, nullptr, kB, vtB,   8192, 1024, 768);

  k_flash<<<dim3(16, 32), 256, 0, stream>>>(qB, kB, vtB, ctxB);

  // car = ctx@Wo + bo + xn (bf16) -> LN3 -> h (bf16)
  k_gemm<64,128,true,true,false,1><<<dim3(4, 128), 256, 0, stream>>>(ctxB, WoT, bo, xnB, nullptr, carB, nullptr, 8192, 512, 512);
  k_layernorm_b<<<8192, 256, 0, stream>>>(carB, ln3g, ln3b, hB);

  // MHA over L=4: in-proj (64x128, ~5 blocks/CU), tiny attention, out-proj
  k_gemm<64,128,true,false,false,1><<<dim3(12, 128), 256, 0, stream>>>(hB, WinT, bin, nullptr, nullptr, qkvB, nullptr, 8192, 1536, 512);
  k_mha_small<<<256, 256, 0, stream>>>(qkvB, saB);
  k_gemm<64,128,true,true,false,1><<<dim3(4, 128), 256, 0, stream>>>(saB, WmoT, bmo, hB, nullptr, sarB, nullptr, 8192, 512, 512);
  k_layernorm_b<<<8192, 256, 0, stream>>>(sarB, ln4g, ln4b, h2B);

  // MLP: GELU(h2@W1 + b1) at 64x128 (~5 blocks/CU); W2 + residual -> d_out
  k_gemm<64,128,true,false,true,1><<<dim3(16, 128), 256, 0, stream>>>(h2B, W1T, b1, nullptr, nullptr, t1B, nullptr, 8192, 2048, 512);
  k_gemm<64,128,true,true,false,0><<<dim3(4, 128), 256, 0, stream>>>(t1B, W2T, b2, h2B, (float*)d_out, nullptr, nullptr, 8192, 512, 2048);
}

// Round 16
// 211.974 us; speedup vs baseline: 1.0237x; 1.0237x over previous
//
#include <hip/hip_runtime.h>
#include <math.h>

typedef unsigned short u16;
typedef __attribute__((ext_vector_type(8))) short bf8;          // 8 x bf16 (4 VGPR) MFMA frag
typedef __attribute__((ext_vector_type(4))) float f4;           // 16x16 MFMA acc
typedef __attribute__((ext_vector_type(16))) float f32x16;      // 32x32 MFMA acc
typedef __attribute__((ext_vector_type(4))) unsigned int u32x4; // 16B staging
typedef __attribute__((ext_vector_type(2))) unsigned int u32x2;
typedef __attribute__((ext_vector_type(4))) unsigned short u16x4;
typedef __attribute__((ext_vector_type(8))) unsigned short u16x8;

__device__ __forceinline__ float bf2f(u16 a){
  unsigned u = ((unsigned)a) << 16;
  float f; __builtin_memcpy(&f, &u, 4);
  return f;
}
__device__ __forceinline__ u16 f2bf(float f){
  unsigned u; __builtin_memcpy(&u, &f, 4);
  u += 0x7fffu + ((u >> 16) & 1u);   // RNE
  return (u16)(u >> 16);
}
// v_cvt_pk_bf16_f32: lo16 = bf16(a), hi16 = bf16(b)
__device__ __forceinline__ unsigned cvtpk(float a, float b){
  unsigned r;
  asm("v_cvt_pk_bf16_f32 %0, %1, %2" : "=v"(r) : "v"(a), "v"(b));
  return r;
}
// v_permlane32_swap_b32
__device__ __forceinline__ void plswap(unsigned &a, unsigned &b){
  asm("v_permlane32_swap_b32 %0, %1" : "+v"(a), "+v"(b));
}
// async global->LDS 16B (dest = wave-uniform base + lane*16)
__device__ __forceinline__ void gload16(const u16* g, u16* l){
  __builtin_amdgcn_global_load_lds((const __attribute__((address_space(1))) void*)g,
                                   (__attribute__((address_space(3))) void*)l, 16, 0, 0);
}
// bijective XCD-chunked block swizzle (m204)
__device__ __forceinline__ int xcd_swizzle(int orig, int nwg){
  const int qq = nwg >> 3, rr = nwg & 7;
  const int xcd = orig & 7, loc = orig >> 3;
  return (xcd < rr ? xcd * (qq + 1) : rr * (qq + 1) + (xcd - rr) * qq) + loc;
}
// exact-enough GELU: x * sigmoid(2 * 0.79788456*(x + 0.044715 x^3))
__device__ __forceinline__ float gelu_f(float v){
  const float vc = fminf(v, 10.f);
  const float z  = vc * (1.f + 0.044715f * vc * vc);   // vc + 0.044715 vc^3
  const float e  = __builtin_amdgcn_exp2f(2.302208499f * z); // 2*0.79788456*log2e
  return v * e * __builtin_amdgcn_rcpf(e + 1.f);
}

// ---------------- fused transpose+cast of all 8 weights ---------------------
__global__ void k_transpose_all(
    const float* __restrict__ Wq, const float* __restrict__ Wk,
    const float* __restrict__ Wv, const float* __restrict__ Wo,
    const float* __restrict__ Win, const float* __restrict__ Wmo,
    const float* __restrict__ W1, const float* __restrict__ W2,
    u16* __restrict__ WqT, u16* __restrict__ WkT, u16* __restrict__ WvT,
    u16* __restrict__ WoT, u16* __restrict__ WinT, u16* __restrict__ WmoT,
    u16* __restrict__ W1T, u16* __restrict__ W2T)
{
  __shared__ float tile[32][33];
  const int tid = blockIdx.x;
  const float* in; u16* out; int R, C, lo;
  if (tid < 1280){
    if (tid < 256)       { in = Wq;  out = WqT;  R = 512; C = 512;  lo = 0; }
    else if (tid < 640)  { in = Wk;  out = WkT;  R = 768; C = 512;  lo = 256; }
    else if (tid < 1024) { in = Wv;  out = WvT;  R = 768; C = 512;  lo = 640; }
    else                 { in = Wo;  out = WoT;  R = 512; C = 512;  lo = 1024; }
  } else {
    if (tid < 2048)      { in = Win; out = WinT; R = 512; C = 1536; lo = 1280; }
    else if (tid < 2304) { in = Wmo; out = WmoT; R = 512; C = 512;  lo = 2048; }
    else if (tid < 3328) { in = W1;  out = W1T;  R = 512; C = 2048; lo = 2304; }
    else                 { in = W2;  out = W2T;  R = 2048; C = 512; lo = 3328; }
  }
  const int local = tid - lo;
  const int tpx = C >> 5;
  const int bx = (local % tpx) * 32, by = (local / tpx) * 32;
  const int tx = threadIdx.x, ty = threadIdx.y;   // (32,8)
#pragma unroll
  for (int i = 0; i < 4; i++)
    tile[ty + i*8][tx] = in[(size_t)(by + ty + i*8) * C + bx + tx];
  __syncthreads();
#pragma unroll
  for (int i = 0; i < 4; i++)
    out[(size_t)(bx + ty + i*8) * R + by + tx] = f2bf(tile[tx][ty + i*8]);
}

// ---------------- LayerNorm (f32 in -> bf16 out) ----------------------------
__device__ __forceinline__ void ln_row_f32(
    const float* __restrict__ r, const float* __restrict__ gam,
    const float* __restrict__ bet, u16* __restrict__ outb, int D, int t)
{
  const int nv = D >> 8;                 // 2 (D=512) or 3 (D=768)
  float v[3] = {0.f, 0.f, 0.f};
  float s = 0.f, s2 = 0.f;
#pragma unroll
  for (int i = 0; i < 3; i++){
    if (i < nv){ float xx = r[t + i*256]; v[i] = xx; s += xx; s2 += xx*xx; }
  }
#pragma unroll
  for (int m = 32; m; m >>= 1){ s += __shfl_xor(s, m); s2 += __shfl_xor(s2, m); }
  __shared__ float rs[4], rq[4];
  const int wave = t >> 6;
  if ((t & 63) == 0){ rs[wave] = s; rq[wave] = s2; }
  __syncthreads();
  s  = rs[0] + rs[1] + rs[2] + rs[3];
  s2 = rq[0] + rq[1] + rq[2] + rq[3];
  const float mean = s / (float)D;
  const float var  = s2 / (float)D - mean * mean;
  const float rstd = rsqrtf(var + 1e-5f);
#pragma unroll
  for (int i = 0; i < 3; i++){
    if (i < nv){
      const int c = t + i*256;
      outb[c] = f2bf((v[i] - mean) * rstd * gam[c] + bet[c]);
    }
  }
}

// fused LN1 (x, D=512) + LN2 (y, D=768), bf16 outputs
__global__ __launch_bounds__(256) void k_layernorm12(
    const float* __restrict__ x, const float* __restrict__ y,
    const float* __restrict__ g1, const float* __restrict__ b1,
    const float* __restrict__ g2, const float* __restrict__ b2,
    u16* __restrict__ xnB, u16* __restrict__ ynB)
{
  const int row = blockIdx.x;
  if (row < 8192){
    ln_row_f32(x + (size_t)row * 512, g1, b1, xnB + (size_t)row * 512, 512, threadIdx.x);
  } else {
    const int r2 = row - 8192;
    ln_row_f32(y + (size_t)r2 * 768, g2, b2, ynB + (size_t)r2 * 768, 768, threadIdx.x);
  }
}

// LayerNorm bf16 in -> bf16 out, D=512 fixed
__global__ __launch_bounds__(256) void k_layernorm_b(
    const u16* __restrict__ in, const float* __restrict__ gam,
    const float* __restrict__ bet, u16* __restrict__ outb)
{
  const int row = blockIdx.x, t = threadIdx.x;
  const u16* r = in + (size_t)row * 512;
  const float v0 = bf2f(r[t]);
  const float v1 = bf2f(r[t + 256]);
  float s = v0 + v1, s2 = v0*v0 + v1*v1;
#pragma unroll
  for (int m = 32; m; m >>= 1){ s += __shfl_xor(s, m); s2 += __shfl_xor(s2, m); }
  __shared__ float rs[4], rq[4];
  const int wave = t >> 6;
  if ((t & 63) == 0){ rs[wave] = s; rq[wave] = s2; }
  __syncthreads();
  s  = rs[0] + rs[1] + rs[2] + rs[3];
  s2 = rq[0] + rq[1] + rq[2] + rq[3];
  const float mean = s * (1.f / 512.f);
  const float var  = s2 * (1.f / 512.f) - mean * mean;
  const float rstd = rsqrtf(var + 1e-5f);
  u16* o = outb + (size_t)row * 512;
  o[t]       = f2bf((v0 - mean) * rstd * gam[t] + bet[t]);
  o[t + 256] = f2bf((v1 - mean) * rstd * gam[t + 256] + bet[t + 256]);
}

// ---------------- bf16 MFMA GEMM (m97 single-buffer) ------------------------
// res input is bf16. OUTM: 0 = f32 out (W2), 1 = bf16 out,
// 2 = bf16 transposed [b*512+n][2048], 3 = fused k|v (n<512 rows | transposed)
// QSC: scale output by 0.125*log2(e) (q-projection feeds exp2-based softmax)
template<int TM, int TN, bool BIAS, bool RES, bool GELU_ACT, int OUTM, bool QSC = false>
__global__ __launch_bounds__(256, 4) void k_gemm(
    const u16* __restrict__ A, const u16* __restrict__ BT,
    const float* __restrict__ bias, const u16* __restrict__ res,
    float* __restrict__ outf, u16* __restrict__ outb, u16* __restrict__ outb2,
    int M, int N, int K)
{
  constexpr int MF = TM / 32;          // 16-row frags per wave (m)
  constexpr int NF = TN / 32;          // 16-col frags per wave (n)
  constexpr int WM = TM / 2;           // wave m-span
  constexpr int WN = TN / 2;           // wave n-span
  __shared__ u16 Sb[(TM + TN) * 64];   // single buffer: A rows then B rows
  const int t = threadIdx.x;
  const int gx = gridDim.x;
  const int swz = xcd_swizzle(blockIdx.y * gx + blockIdx.x, gx * gridDim.y);
  const int m0 = (swz / gx) * TM, n0 = (swz % gx) * TN;
  const int wave = t >> 6, lane = t & 63;
  const int wm = wave >> 1, wn = wave & 1;
  const int l15 = lane & 15, lg = lane >> 4;
  const u16* Ag = A + (size_t)m0 * K;
  const u16* Bg = BT + (size_t)n0 * K;

  const int lrow = lane >> 3;                       // row within 8-row slice
  const int csrc = (((lane & 7) ^ lrow) << 3);      // swizzled col (elements)
  const u16* Agl = Ag + (size_t)lrow * K + csrc;
  const u16* Bgl = Bg + (size_t)lrow * K + csrc;

  f4 acc[MF][NF];
#pragma unroll
  for (int i = 0; i < MF; i++)
#pragma unroll
    for (int j = 0; j < NF; j++) acc[i][j] = (f4){0.f, 0.f, 0.f, 0.f};

  const int nK = K >> 6;
  // prologue: stage tile 0
#pragma unroll
  for (int i = 0; i < TM/32; i++){
    const int rb = (i*4 + wave) * 8;
    gload16(Agl + (size_t)rb * K, &Sb[rb * 64]);
  }
#pragma unroll
  for (int i = 0; i < TN/32; i++){
    const int rb = (i*4 + wave) * 8;
    gload16(Bgl + (size_t)rb * K, &Sb[(TM + rb) * 64]);
  }
  asm volatile("s_waitcnt vmcnt(0)" ::: "memory");
  __syncthreads();

  for (int kt = 0;; kt++){
    const char* As = (const char*)&Sb[0];
    const char* Bs = (const char*)&Sb[TM * 64];
#pragma unroll
    for (int kc = 0; kc < 2; kc++){
      bf8 af[MF], bfr[NF];
      const int kb = kc*64 + lg*16;                     // byte offset in row
#pragma unroll
      for (int mf = 0; mf < MF; mf++){
        const int row = wm*WM + mf*16 + l15;
        af[mf] = *(const bf8*)(As + row*128 + (kb ^ ((row & 7) << 4)));
      }
#pragma unroll
      for (int nf = 0; nf < NF; nf++){
        const int row = wn*WN + nf*16 + l15;
        bfr[nf] = *(const bf8*)(Bs + row*128 + (kb ^ ((row & 7) << 4)));
      }
#pragma unroll
      for (int mf = 0; mf < MF; mf++)
#pragma unroll
        for (int nf = 0; nf < NF; nf++)
          acc[mf][nf] = __builtin_amdgcn_mfma_f32_16x16x32_bf16(af[mf], bfr[nf], acc[mf][nf], 0, 0, 0);
    }
    if (kt + 1 == nK) break;
    __syncthreads();                       // all reads of Sb done
    const int ko = (kt + 1) << 6;
#pragma unroll
    for (int i = 0; i < TM/32; i++){
      const int rb = (i*4 + wave) * 8;
      gload16(Agl + (size_t)rb * K + ko, &Sb[rb * 64]);
    }
#pragma unroll
    for (int i = 0; i < TN/32; i++){
      const int rb = (i*4 + wave) * 8;
      gload16(Bgl + (size_t)rb * K + ko, &Sb[(TM + rb) * 64]);
    }
    asm volatile("s_waitcnt vmcnt(0)" ::: "memory");
    __syncthreads();                       // staged & visible
  }
  // epilogue
#pragma unroll
  for (int mf = 0; mf < MF; mf++){
#pragma unroll
    for (int nf = 0; nf < NF; nf++){
      const int colg = n0 + wn*WN + nf*16 + l15;
      const int rowg = m0 + wm*WM + mf*16 + lg*4;
      const float bv = BIAS ? bias[colg] : 0.f;
      float vv[4];
#pragma unroll
      for (int j = 0; j < 4; j++){
        float v = acc[mf][nf][j] + bv;
        if (RES) v += bf2f(res[(size_t)(rowg + j) * N + colg]);
        if (GELU_ACT) v = gelu_f(v);
        if (QSC) v *= 0.1803368801f;       // 0.125 * log2(e)
        vv[j] = v;
      }
      if (OUTM == 0){
#pragma unroll
        for (int j = 0; j < 4; j++) outf[(size_t)(rowg + j) * N + colg] = vv[j];
      } else if (OUTM == 1){
#pragma unroll
        for (int j = 0; j < 4; j++) outb[(size_t)(rowg + j) * N + colg] = f2bf(vv[j]);
      } else if (OUTM == 2){
        const int bb = rowg >> 11, ss = rowg & 2047;    // per-batch transpose
        u16x4 pk;
#pragma unroll
        for (int j = 0; j < 4; j++) pk[j] = f2bf(vv[j]);
        *(u16x4*)(outb + ((size_t)(bb*512 + colg)) * 2048 + ss) = pk;
      } else {                                          // OUTM 3: fused k|v
        if (n0 < 512){
#pragma unroll
          for (int j = 0; j < 4; j++) outb[(size_t)(rowg + j) * 512 + colg] = f2bf(vv[j]);
        } else {
          const int bb = rowg >> 11, ss = rowg & 2047;
          u16x4 pk;
#pragma unroll
          for (int j = 0; j < 4; j++) pk[j] = f2bf(vv[j]);
          *(u16x4*)(outb2 + ((size_t)(bb*512 + (colg - 512))) * 2048 + ss) = pk;
        }
      }
    }
  }
}

// ---------------- flash cross-attention v8: KVBLK=128, 48KB LDS -------------
// q pre-scaled by 0.125*log2e -> p = exp2(s). no-max softmax (tiny scores).
// K single-buffered (QK reads fenced by barrier B before restage); V double-
// buffered (staged right after barrier A). Softmax interleaved with PV MFMAs.
__global__ __launch_bounds__(256, 3) void k_flash(
    const u16* __restrict__ q, const u16* __restrict__ k,
    const u16* __restrict__ vt, u16* __restrict__ ctx)
{
  __shared__ u16 Kb[128 * 64];         // [key 128][d 64], 128B rows, swizzled
  __shared__ u16 Vb[2][64 * 128];      // [d 64][key 128], 256B rows, swizzled
  const int t = threadIdx.x;
  const int wave = t >> 6, lane = t & 63;
  const int l31 = lane & 31, hi = lane >> 5;
  const int id = blockIdx.y * 16 + blockIdx.x;   // bh*16 + qb
  const int swz = xcd_swizzle(id, 512);
  const int qb = swz & 15, bh = swz >> 4;
  const int b = bh >> 3, h = bh & 7;
  const int qrow0 = qb*128 + wave*32;

  // Q B-frags: qf[ds] = Q[qrow0+l31][h*64 + ds*16 + hi*8 .. +7]
  bf8 qf[4];
  {
    const u16* qp = q + ((size_t)(b*2048 + qrow0 + l31)) * 512 + h*64 + hi*8;
    qf[0] = *(const bf8*)qp;
    qf[1] = *(const bf8*)(qp + 16);
    qf[2] = *(const bf8*)(qp + 32);
    qf[3] = *(const bf8*)(qp + 48);
  }

  // K staging: 8 rows x 128B per gload, pre-swizzled source col
  const int lrow8 = lane >> 3;
  const int csK = (((lane & 7) ^ lrow8) << 3);
  const u16* kgl = k + ((size_t)(b*2048 + lrow8)) * 512 + h*64 + csK;
  // V staging: 4 rows x 256B per gload; swizzle parity depends on slice
  const int lrow4 = lane >> 4;
  const int csVe = (((lane & 15) ^ lrow4) << 3);        // slice%2==0: row&7 = lrow4
  const int csVo = (((lane & 15) ^ (4 + lrow4)) << 3);  // slice%2==1: row&7 = 4+lrow4
  const u16* vrow = vt + ((size_t)(b*512 + h*64 + lrow4)) * 2048;

  f32x16 o0, o1;
#pragma unroll
  for (int r = 0; r < 16; r++){ o0[r] = 0.f; o1[r] = 0.f; }
  float rl = 0.f;

  // prologue: stage tile 0 (K -> Kb, V -> Vb[0])
#pragma unroll
  for (int i = 0; i < 4; i++){
    const int rb = (i*4 + wave) * 8;
    gload16(kgl + (size_t)rb * 512, &Kb[rb * 64]);
    const int sl = i*4 + wave;
    gload16(vrow + (size_t)(sl*4) * 2048 + ((sl & 1) ? csVo : csVe), &Vb[0][sl * 512]);
  }

  int cur = 0;
  for (int it = 0; it < 16; it++){
    asm volatile("s_waitcnt vmcnt(0)" ::: "memory");
    __syncthreads();                       // A: K = tile it, V[cur] = tile it
    if (it + 1 < 16){                      // stage V(it+1) early (V[cur^1] free)
      const int kt = (it + 1) << 7;
#pragma unroll
      for (int i = 0; i < 4; i++){
        const int sl = i*4 + wave;
        gload16(vrow + (size_t)(sl*4) * 2048 + kt + ((sl & 1) ? csVo : csVe),
                &Vb[cur^1][sl * 512]);
      }
    }
    const char* kbuf = (const char*)Kb;
    const char* vbuf = (const char*)Vb[cur];
    // QK^T swapped, 32x32x16: s{krf} covers keys krf*32..+31 for q=l31
    f32x16 s0, s1, s2, s3;
#pragma unroll
    for (int r = 0; r < 16; r++){ s0[r] = 0.f; s1[r] = 0.f; s2[r] = 0.f; s3[r] = 0.f; }
    __builtin_amdgcn_s_setprio(1);
#pragma unroll
    for (int ds = 0; ds < 4; ds++){
      const int off = ds*32 + hi*16;
      const int r0 = l31, r1 = 32 + l31, r2 = 64 + l31, r3 = 96 + l31;
      const bf8 k0 = *(const bf8*)(kbuf + r0*128 + (off ^ ((r0 & 7) << 4)));
      const bf8 k1 = *(const bf8*)(kbuf + r1*128 + (off ^ ((r1 & 7) << 4)));
      const bf8 k2 = *(const bf8*)(kbuf + r2*128 + (off ^ ((r2 & 7) << 4)));
      const bf8 k3 = *(const bf8*)(kbuf + r3*128 + (off ^ ((r3 & 7) << 4)));
      s0 = __builtin_amdgcn_mfma_f32_32x32x16_bf16(k0, qf[ds], s0, 0, 0, 0);
      s1 = __builtin_amdgcn_mfma_f32_32x32x16_bf16(k1, qf[ds], s1, 0, 0, 0);
      s2 = __builtin_amdgcn_mfma_f32_32x32x16_bf16(k2, qf[ds], s2, 0, 0, 0);
      s3 = __builtin_amdgcn_mfma_f32_32x32x16_bf16(k3, qf[ds], s3, 0, 0, 0);
    }
    __builtin_amdgcn_s_setprio(0);
    __syncthreads();                       // B: all QK reads of Kb done
    if (it + 1 < 16){                      // restage K (async, lands by next A)
      const int kt = (it + 1) << 7;
#pragma unroll
      for (int i = 0; i < 4; i++){
        const int rb = (i*4 + wave) * 8;
        gload16(kgl + (size_t)(kt + rb) * 512, &Kb[rb * 64]);
      }
    }
    // softmax (no max-shift) + pack, interleaved with PV per 32-key sub-tile
    float rsum = 0.f;
#define SMPV(SV, SUB)                                                          \
    {                                                                          \
      float pp[16];                                                            \
      _Pragma("unroll")                                                        \
      for (int r = 0; r < 16; r++) pp[r] = __builtin_amdgcn_exp2f(SV[r]);      \
      _Pragma("unroll")                                                        \
      for (int r = 0; r < 16; r++) rsum += pp[r];                              \
      unsigned w0 = cvtpk(pp[0],  pp[1]),  w1 = cvtpk(pp[2],  pp[3]);          \
      unsigned w2 = cvtpk(pp[4],  pp[5]),  w3 = cvtpk(pp[6],  pp[7]);          \
      unsigned w4 = cvtpk(pp[8],  pp[9]),  w5 = cvtpk(pp[10], pp[11]);         \
      unsigned w6 = cvtpk(pp[12], pp[13]), w7 = cvtpk(pp[14], pp[15]);         \
      plswap(w0, w2); plswap(w1, w3);                                          \
      plswap(w4, w6); plswap(w5, w7);                                          \
      u32x4 t0 = {w0, w1, w2, w3};                                             \
      u32x4 t1 = {w4, w5, w6, w7};                                             \
      bf8 pa0, pa1;                                                            \
      __builtin_memcpy(&pa0, &t0, 16);                                         \
      __builtin_memcpy(&pa1, &t1, 16);                                         \
      const int off0 = SUB*64 + hi*16;                                         \
      const int off1 = SUB*64 + 32 + hi*16;                                    \
      const int r0 = l31, r1 = 32 + l31;                                       \
      const bf8 va0 = *(const bf8*)(vbuf + r0*256 + (off0 ^ ((r0 & 7) << 4))); \
      const bf8 va1 = *(const bf8*)(vbuf + r1*256 + (off0 ^ ((r1 & 7) << 4))); \
      const bf8 vb0 = *(const bf8*)(vbuf + r0*256 + (off1 ^ ((r0 & 7) << 4))); \
      const bf8 vb1 = *(const bf8*)(vbuf + r1*256 + (off1 ^ ((r1 & 7) << 4))); \
      o0 = __builtin_amdgcn_mfma_f32_32x32x16_bf16(pa0, va0, o0, 0, 0, 0);     \
      o1 = __builtin_amdgcn_mfma_f32_32x32x16_bf16(pa0, va1, o1, 0, 0, 0);     \
      o0 = __builtin_amdgcn_mfma_f32_32x32x16_bf16(pa1, vb0, o0, 0, 0, 0);     \
      o1 = __builtin_amdgcn_mfma_f32_32x32x16_bf16(pa1, vb1, o1, 0, 0, 0);     \
    }
    SMPV(s0, 0)
    SMPV(s1, 1)
    SMPV(s2, 2)
    SMPV(s3, 3)
#undef SMPV
    rsum += __shfl_xor(rsum, 32);
    rl += rsum;
    cur ^= 1;
  }
  // epilogue: divide by row sum, write ctx. o reg r: q = (r&3)+8*(r>>2)+4*hi,
  // d = dfrag*32 + l31.
  const float linv = 1.f / rl;             // valid for q = l31
#pragma unroll
  for (int r = 0; r < 16; r++){
    const int crow = (r & 3) + 8*(r >> 2) + 4*hi;
    const float iv = __shfl(linv, crow);
    u16* cp = ctx + ((size_t)(b*2048 + qrow0 + crow)) * 512 + h*64 + l31;
    cp[0]  = f2bf(o0[r] * iv);
    cp[32] = f2bf(o1[r] * iv);
  }
}

// ---------------- tiny MHA (batch_first=False: attends over L=4) ------------
__global__ __launch_bounds__(256) void k_mha_small(const u16* __restrict__ qkv,
                                                   u16* __restrict__ outb)
{
  const int tid = blockIdx.x * 256 + threadIdx.x;  // 65536 threads
  const int n = tid & 2047;
  const int hl = tid >> 11;
  const int h = hl >> 2, l = hl & 3;
  const u16* qp = qkv + ((size_t)l * 2048 + n) * 1536 + h*64;
  float qv[64];
#pragma unroll
  for (int i = 0; i < 8; i++){
    const bf8 c = *(const bf8*)(qp + i*8);
#pragma unroll
    for (int j2 = 0; j2 < 8; j2++) qv[i*8 + j2] = bf2f((u16)c[j2]) * 0.125f;
  }
  float sc[4];
#pragma unroll
  for (int m = 0; m < 4; m++){
    const u16* kp = qkv + ((size_t)m * 2048 + n) * 1536 + 512 + h*64;
    float a = 0.f;
#pragma unroll
    for (int i = 0; i < 8; i++){
      const bf8 c = *(const bf8*)(kp + i*8);
#pragma unroll
      for (int j2 = 0; j2 < 8; j2++) a += qv[i*8 + j2] * bf2f((u16)c[j2]);
    }
    sc[m] = a;
  }
  const float mx = fmaxf(fmaxf(sc[0], sc[1]), fmaxf(sc[2], sc[3]));
  float p[4]; float sum = 0.f;
#pragma unroll
  for (int m = 0; m < 4; m++){ p[m] = __expf(sc[m] - mx); sum += p[m]; }
  const float inv = 1.f / sum;
  float ov[64];
#pragma unroll
  for (int i = 0; i < 64; i++) ov[i] = 0.f;
#pragma unroll
  for (int m = 0; m < 4; m++){
    const float pw = p[m] * inv;
    const u16* vp = qkv + ((size_t)m * 2048 + n) * 1536 + 1024 + h*64;
#pragma unroll
    for (int i = 0; i < 8; i++){
      const bf8 c = *(const bf8*)(vp + i*8);
#pragma unroll
      for (int j2 = 0; j2 < 8; j2++) ov[i*8 + j2] += pw * bf2f((u16)c[j2]);
    }
  }
  u16* op = outb + ((size_t)l * 2048 + n) * 512 + h*64;
#pragma unroll
  for (int i = 0; i < 8; i++){
    u16x8 pk;
#pragma unroll
    for (int j2 = 0; j2 < 8; j2++) pk[j2] = f2bf(ov[i*8 + j2]);
    *(u16x8*)(op + i*8) = pk;
  }
}

// ---------------------------------------------------------------------------
extern "C" void kernel_launch(void* const* d_in, const int* in_sizes, int n_in,
                              void* d_out, int out_size, void* d_ws, size_t ws_size,
                              hipStream_t stream)
{
  (void)in_sizes; (void)n_in; (void)out_size; (void)ws_size;
  const float* x    = (const float*)d_in[0];
  const float* y    = (const float*)d_in[1];
  const float* Wq   = (const float*)d_in[2];
  const float* Wk   = (const float*)d_in[3];
  const float* Wv   = (const float*)d_in[4];
  const float* Wo   = (const float*)d_in[5];
  const float* bo   = (const float*)d_in[6];
  const float* Win  = (const float*)d_in[7];
  const float* bin  = (const float*)d_in[8];
  const float* Wmo  = (const float*)d_in[9];
  const float* bmo  = (const float*)d_in[10];
  const float* ln1g = (const float*)d_in[11];
  const float* ln1b = (const float*)d_in[12];
  const float* ln2g = (const float*)d_in[13];
  const float* ln2b = (const float*)d_in[14];
  const float* ln3g = (const float*)d_in[15];
  const float* ln3b = (const float*)d_in[16];
  const float* ln4g = (const float*)d_in[17];
  const float* ln4b = (const float*)d_in[18];
  const float* W1   = (const float*)d_in[19];
  const float* b1   = (const float*)d_in[20];
  const float* W2   = (const float*)d_in[21];
  const float* b2   = (const float*)d_in[22];

  char* ws = (char*)d_ws;
  const size_t MB = 1024 * 1024;
  // bf16 transposed weights (~8.5 MB); WkT and WvT adjacent -> fused k|v GEMM
  u16* WqT  = (u16*)ws;
  u16* WkT  = WqT  + 512 * 512;
  u16* WvT  = WkT  + 512 * 768;
  u16* WoT  = WvT  + 512 * 768;
  u16* WinT = WoT  + 512 * 512;
  u16* WmoT = WinT + 1536 * 512;
  u16* W1T  = WmoT + 512 * 512;
  u16* W2T  = W1T  + 2048 * 512;
  // all-bf16 activation buffers with lifetime-based aliasing (<=109 MB)
  u16* xnB  = (u16*)(ws +   9 * MB);  // 8MB  LN1 out; res for Wo
  u16* ynB  = (u16*)(ws +  17 * MB);  // 12MB LN2 out
  u16* qB   = (u16*)(ws +  29 * MB);  // 8MB  q (pre-scaled); dead after flash
  u16* kB   = (u16*)(ws +  37 * MB);  // 8MB  k; dead after flash
  u16* vtB  = (u16*)(ws +  45 * MB);  // 8MB  v^T; dead after flash
  u16* ctxB = (u16*)(ws +  53 * MB);  // 8MB  flash out; dead after Wo
  u16* carB = (u16*)(ws +  61 * MB);  // 8MB  ca+xn; dead after LN3
  u16* hB   = (u16*)(ws +  69 * MB);  // 8MB  LN3 out; res for Wmo
  u16* qkvB = (u16*)(ws +  77 * MB);  // 24MB Win out; dead after mha
  u16* saB  = (u16*)(ws + 101 * MB);  // 8MB  mha out
  u16* sarB = qB;                     // sa+h (qB dead)
  u16* h2B  = kB;                     // LN4 out (kB dead)
  u16* t1B  = vtB;                    // 32MB GELU(..) spans 45..77 (all dead)

  k_transpose_all<<<4352, dim3(32, 8), 0, stream>>>(
      Wq, Wk, Wv, Wo, Win, Wmo, W1, W2,
      WqT, WkT, WvT, WoT, WinT, WmoT, W1T, W2T);

  k_layernorm12<<<16384, 256, 0, stream>>>(x, y, ln1g, ln1b, ln2g, ln2b, xnB, ynB);

  // q projection (pre-scaled for exp2 softmax); fused k|v projection
  k_gemm<64,128,false,false,false,1,true><<<dim3(4, 128), 256, 0, stream>>>(xnB, WqT, nullptr, nullptr, nullptr, qB, nullptr, 8192, 512, 512);
  k_gemm<64,128,false,false,false,3><<<dim3(8, 128), 256, 0, stream>>>(ynB, WkT, nullptr, nullptr, nullptr, kB, vtB,   8192, 1024, 768);

  k_flash<<<dim3(16, 32), 256, 0, stream>>>(qB, kB, vtB, ctxB);

  // car = ctx@Wo + bo + xn (bf16) -> LN3 -> h (bf16)
  k_gemm<64,128,true,true,false,1><<<dim3(4, 128), 256, 0, stream>>>(ctxB, WoT, bo, xnB, nullptr, carB, nullptr, 8192, 512, 512);
  k_layernorm_b<<<8192, 256, 0, stream>>>(carB, ln3g, ln3b, hB);

  // MHA over L=4: in-proj (128x128), tiny attention, out-proj -> LN4 -> h2
  k_gemm<128,128,true,false,false,1><<<dim3(12, 64), 256, 0, stream>>>(hB, WinT, bin, nullptr, nullptr, qkvB, nullptr, 8192, 1536, 512);
  k_mha_small<<<256, 256, 0, stream>>>(qkvB, saB);
  k_gemm<64,128,true,true,false,1><<<dim3(4, 128), 256, 0, stream>>>(saB, WmoT, bmo, hB, nullptr, sarB, nullptr, 8192, 512, 512);
  k_layernorm_b<<<8192, 256, 0, stream>>>(sarB, ln4g, ln4b, h2B);

  // MLP: GELU(h2@W1 + b1) at 128x128; W2 + residual -> d_out (f32)
  k_gemm<128,128,true,false,true,1><<<dim3(16, 64), 256, 0, stream>>>(h2B, W1T, b1, nullptr, nullptr, t1B, nullptr, 8192, 2048, 512);
  k_gemm<64,128,true,true,false,0><<<dim3(4, 128), 256, 0, stream>>>(t1B, W2T, b2, h2B, (float*)d_out, nullptr, nullptr, 8192, 512, 2048);
}

// Round 17
// 203.886 us; speedup vs baseline: 1.0643x; 1.0397x over previous
//
#include <hip/hip_runtime.h>
#include <math.h>

typedef unsigned short u16;
typedef __attribute__((ext_vector_type(8))) short bf8;          // 8 x bf16 (4 VGPR) MFMA frag
typedef __attribute__((ext_vector_type(4))) float f4;           // 16x16 MFMA acc
typedef __attribute__((ext_vector_type(16))) float f32x16;      // 32x32 MFMA acc
typedef __attribute__((ext_vector_type(4))) unsigned int u32x4; // 16B staging
typedef __attribute__((ext_vector_type(2))) unsigned int u32x2;
typedef __attribute__((ext_vector_type(4))) unsigned short u16x4;
typedef __attribute__((ext_vector_type(8))) unsigned short u16x8;

__device__ __forceinline__ float bf2f(u16 a){
  unsigned u = ((unsigned)a) << 16;
  float f; __builtin_memcpy(&f, &u, 4);
  return f;
}
__device__ __forceinline__ u16 f2bf(float f){
  unsigned u; __builtin_memcpy(&u, &f, 4);
  u += 0x7fffu + ((u >> 16) & 1u);   // RNE
  return (u16)(u >> 16);
}
// v_cvt_pk_bf16_f32: lo16 = bf16(a), hi16 = bf16(b)
__device__ __forceinline__ unsigned cvtpk(float a, float b){
  unsigned r;
  asm("v_cvt_pk_bf16_f32 %0, %1, %2" : "=v"(r) : "v"(a), "v"(b));
  return r;
}
// v_permlane32_swap_b32
__device__ __forceinline__ void plswap(unsigned &a, unsigned &b){
  asm("v_permlane32_swap_b32 %0, %1" : "+v"(a), "+v"(b));
}
// async global->LDS 16B (dest = wave-uniform base + lane*16)
__device__ __forceinline__ void gload16(const u16* g, u16* l){
  __builtin_amdgcn_global_load_lds((const __attribute__((address_space(1))) void*)g,
                                   (__attribute__((address_space(3))) void*)l, 16, 0, 0);
}
// bijective XCD-chunked block swizzle (m204)
__device__ __forceinline__ int xcd_swizzle(int orig, int nwg){
  const int qq = nwg >> 3, rr = nwg & 7;
  const int xcd = orig & 7, loc = orig >> 3;
  return (xcd < rr ? xcd * (qq + 1) : rr * (qq + 1) + (xcd - rr) * qq) + loc;
}
// exact-enough GELU: x * sigmoid(2 * 0.79788456*(x + 0.044715 x^3))
__device__ __forceinline__ float gelu_f(float v){
  const float vc = fminf(v, 10.f);
  const float z  = vc * (1.f + 0.044715f * vc * vc);   // vc + 0.044715 vc^3
  const float e  = __builtin_amdgcn_exp2f(2.302208499f * z); // 2*0.79788456*log2e
  return v * e * __builtin_amdgcn_rcpf(e + 1.f);
}

// ---------------- LayerNorm row helper (f32 in -> bf16 out) -----------------
__device__ __forceinline__ void ln_row_f32(
    const float* __restrict__ r, const float* __restrict__ gam,
    const float* __restrict__ bet, u16* __restrict__ outb, int D, int t)
{
  const int nv = D >> 8;                 // 2 (D=512) or 3 (D=768)
  float v[3] = {0.f, 0.f, 0.f};
  float s = 0.f, s2 = 0.f;
#pragma unroll
  for (int i = 0; i < 3; i++){
    if (i < nv){ float xx = r[t + i*256]; v[i] = xx; s += xx; s2 += xx*xx; }
  }
#pragma unroll
  for (int m = 32; m; m >>= 1){ s += __shfl_xor(s, m); s2 += __shfl_xor(s2, m); }
  __shared__ float rs[4], rq[4];
  const int wave = t >> 6;
  if ((t & 63) == 0){ rs[wave] = s; rq[wave] = s2; }
  __syncthreads();
  s  = rs[0] + rs[1] + rs[2] + rs[3];
  s2 = rq[0] + rq[1] + rq[2] + rq[3];
  const float mean = s / (float)D;
  const float var  = s2 / (float)D - mean * mean;
  const float rstd = rsqrtf(var + 1e-5f);
#pragma unroll
  for (int i = 0; i < 3; i++){
    if (i < nv){
      const int c = t + i*256;
      outb[c] = f2bf((v[i] - mean) * rstd * gam[c] + bet[c]);
    }
  }
}

// ---------------- fused prologue: LN1 + LN2 + all 8 weight transposes -------
__global__ __launch_bounds__(256) void k_prologue(
    const float* __restrict__ x, const float* __restrict__ y,
    const float* __restrict__ g1, const float* __restrict__ b1,
    const float* __restrict__ g2, const float* __restrict__ b2,
    u16* __restrict__ xnB, u16* __restrict__ ynB,
    const float* __restrict__ Wq, const float* __restrict__ Wk,
    const float* __restrict__ Wv, const float* __restrict__ Wo,
    const float* __restrict__ Win, const float* __restrict__ Wmo,
    const float* __restrict__ W1, const float* __restrict__ W2,
    u16* __restrict__ WqT, u16* __restrict__ WkT, u16* __restrict__ WvT,
    u16* __restrict__ WoT, u16* __restrict__ WinT, u16* __restrict__ WmoT,
    u16* __restrict__ W1T, u16* __restrict__ W2T)
{
  __shared__ float tile[32][33];
  const int bid = blockIdx.x;
  if (bid < 16384){
    if (bid < 8192){
      ln_row_f32(x + (size_t)bid * 512, g1, b1, xnB + (size_t)bid * 512, 512, threadIdx.x);
    } else {
      const int r2 = bid - 8192;
      ln_row_f32(y + (size_t)r2 * 768, g2, b2, ynB + (size_t)r2 * 768, 768, threadIdx.x);
    }
    return;
  }
  const int tid = bid - 16384;
  const float* in; u16* out; int R, C, lo;
  if (tid < 1280){
    if (tid < 256)       { in = Wq;  out = WqT;  R = 512; C = 512;  lo = 0; }
    else if (tid < 640)  { in = Wk;  out = WkT;  R = 768; C = 512;  lo = 256; }
    else if (tid < 1024) { in = Wv;  out = WvT;  R = 768; C = 512;  lo = 640; }
    else                 { in = Wo;  out = WoT;  R = 512; C = 512;  lo = 1024; }
  } else {
    if (tid < 2048)      { in = Win; out = WinT; R = 512; C = 1536; lo = 1280; }
    else if (tid < 2304) { in = Wmo; out = WmoT; R = 512; C = 512;  lo = 2048; }
    else if (tid < 3328) { in = W1;  out = W1T;  R = 512; C = 2048; lo = 2304; }
    else                 { in = W2;  out = W2T;  R = 2048; C = 512; lo = 3328; }
  }
  const int local = tid - lo;
  const int tpx = C >> 5;
  const int bx = (local % tpx) * 32, by = (local / tpx) * 32;
  const int tx = threadIdx.x & 31, ty = threadIdx.x >> 5;   // 32 x 8
#pragma unroll
  for (int i = 0; i < 4; i++)
    tile[ty + i*8][tx] = in[(size_t)(by + ty + i*8) * C + bx + tx];
  __syncthreads();
#pragma unroll
  for (int i = 0; i < 4; i++)
    out[(size_t)(bx + ty + i*8) * R + by + tx] = f2bf(tile[tx][ty + i*8]);
}

// LayerNorm bf16 in -> bf16 out, D=512 fixed
__global__ __launch_bounds__(256) void k_layernorm_b(
    const u16* __restrict__ in, const float* __restrict__ gam,
    const float* __restrict__ bet, u16* __restrict__ outb)
{
  const int row = blockIdx.x, t = threadIdx.x;
  const u16* r = in + (size_t)row * 512;
  const float v0 = bf2f(r[t]);
  const float v1 = bf2f(r[t + 256]);
  float s = v0 + v1, s2 = v0*v0 + v1*v1;
#pragma unroll
  for (int m = 32; m; m >>= 1){ s += __shfl_xor(s, m); s2 += __shfl_xor(s2, m); }
  __shared__ float rs[4], rq[4];
  const int wave = t >> 6;
  if ((t & 63) == 0){ rs[wave] = s; rq[wave] = s2; }
  __syncthreads();
  s  = rs[0] + rs[1] + rs[2] + rs[3];
  s2 = rq[0] + rq[1] + rq[2] + rq[3];
  const float mean = s * (1.f / 512.f);
  const float var  = s2 * (1.f / 512.f) - mean * mean;
  const float rstd = rsqrtf(var + 1e-5f);
  u16* o = outb + (size_t)row * 512;
  o[t]       = f2bf((v0 - mean) * rstd * gam[t] + bet[t]);
  o[t + 256] = f2bf((v1 - mean) * rstd * gam[t + 256] + bet[t + 256]);
}

// ---------------- bf16 MFMA GEMM body (m97 single-buffer) -------------------
// res input is bf16. OUTM: 0 = f32 out (W2), 1 = bf16 out,
// 2 = bf16 transposed [b*512+n][2048], 3 = fused k|v (n<512 rows | transposed)
// QSC: scale output by 0.125*log2(e) (q-projection feeds exp2-based softmax)
template<int TM, int TN, bool BIAS, bool RES, bool GELU_ACT, int OUTM, bool QSC>
__device__ __forceinline__ void gemm_body(
    u16* Sb, int bid, int gx, int nwg,
    const u16* __restrict__ A, const u16* __restrict__ BT,
    const float* __restrict__ bias, const u16* __restrict__ res,
    float* __restrict__ outf, u16* __restrict__ outb, u16* __restrict__ outb2,
    int M, int N, int K)
{
  constexpr int MF = TM / 32;          // 16-row frags per wave (m)
  constexpr int NF = TN / 32;          // 16-col frags per wave (n)
  constexpr int WM = TM / 2;           // wave m-span
  constexpr int WN = TN / 2;           // wave n-span
  const int t = threadIdx.x;
  const int swz = xcd_swizzle(bid, nwg);
  const int m0 = (swz / gx) * TM, n0 = (swz % gx) * TN;
  const int wave = t >> 6, lane = t & 63;
  const int wm = wave >> 1, wn = wave & 1;
  const int l15 = lane & 15, lg = lane >> 4;
  const u16* Ag = A + (size_t)m0 * K;
  const u16* Bg = BT + (size_t)n0 * K;

  const int lrow = lane >> 3;                       // row within 8-row slice
  const int csrc = (((lane & 7) ^ lrow) << 3);      // swizzled col (elements)
  const u16* Agl = Ag + (size_t)lrow * K + csrc;
  const u16* Bgl = Bg + (size_t)lrow * K + csrc;

  f4 acc[MF][NF];
#pragma unroll
  for (int i = 0; i < MF; i++)
#pragma unroll
    for (int j = 0; j < NF; j++) acc[i][j] = (f4){0.f, 0.f, 0.f, 0.f};

  const int nK = K >> 6;
  // prologue: stage tile 0
#pragma unroll
  for (int i = 0; i < TM/32; i++){
    const int rb = (i*4 + wave) * 8;
    gload16(Agl + (size_t)rb * K, &Sb[rb * 64]);
  }
#pragma unroll
  for (int i = 0; i < TN/32; i++){
    const int rb = (i*4 + wave) * 8;
    gload16(Bgl + (size_t)rb * K, &Sb[(TM + rb) * 64]);
  }
  asm volatile("s_waitcnt vmcnt(0)" ::: "memory");
  __syncthreads();

  for (int kt = 0;; kt++){
    const char* As = (const char*)&Sb[0];
    const char* Bs = (const char*)&Sb[TM * 64];
#pragma unroll
    for (int kc = 0; kc < 2; kc++){
      bf8 af[MF], bfr[NF];
      const int kb = kc*64 + lg*16;                     // byte offset in row
#pragma unroll
      for (int mf = 0; mf < MF; mf++){
        const int row = wm*WM + mf*16 + l15;
        af[mf] = *(const bf8*)(As + row*128 + (kb ^ ((row & 7) << 4)));
      }
#pragma unroll
      for (int nf = 0; nf < NF; nf++){
        const int row = wn*WN + nf*16 + l15;
        bfr[nf] = *(const bf8*)(Bs + row*128 + (kb ^ ((row & 7) << 4)));
      }
#pragma unroll
      for (int mf = 0; mf < MF; mf++)
#pragma unroll
        for (int nf = 0; nf < NF; nf++)
          acc[mf][nf] = __builtin_amdgcn_mfma_f32_16x16x32_bf16(af[mf], bfr[nf], acc[mf][nf], 0, 0, 0);
    }
    if (kt + 1 == nK) break;
    __syncthreads();                       // all reads of Sb done
    const int ko = (kt + 1) << 6;
#pragma unroll
    for (int i = 0; i < TM/32; i++){
      const int rb = (i*4 + wave) * 8;
      gload16(Agl + (size_t)rb * K + ko, &Sb[rb * 64]);
    }
#pragma unroll
    for (int i = 0; i < TN/32; i++){
      const int rb = (i*4 + wave) * 8;
      gload16(Bgl + (size_t)rb * K + ko, &Sb[(TM + rb) * 64]);
    }
    asm volatile("s_waitcnt vmcnt(0)" ::: "memory");
    __syncthreads();                       // staged & visible
  }
  // epilogue
#pragma unroll
  for (int mf = 0; mf < MF; mf++){
#pragma unroll
    for (int nf = 0; nf < NF; nf++){
      const int colg = n0 + wn*WN + nf*16 + l15;
      const int rowg = m0 + wm*WM + mf*16 + lg*4;
      const float bv = BIAS ? bias[colg] : 0.f;
      float vv[4];
#pragma unroll
      for (int j = 0; j < 4; j++){
        float v = acc[mf][nf][j] + bv;
        if (RES) v += bf2f(res[(size_t)(rowg + j) * N + colg]);
        if (GELU_ACT) v = gelu_f(v);
        if (QSC) v *= 0.1803368801f;       // 0.125 * log2(e)
        vv[j] = v;
      }
      if (OUTM == 0){
#pragma unroll
        for (int j = 0; j < 4; j++) outf[(size_t)(rowg + j) * N + colg] = vv[j];
      } else if (OUTM == 1){
#pragma unroll
        for (int j = 0; j < 4; j++) outb[(size_t)(rowg + j) * N + colg] = f2bf(vv[j]);
      } else if (OUTM == 2){
        const int bb = rowg >> 11, ss = rowg & 2047;    // per-batch transpose
        u16x4 pk;
#pragma unroll
        for (int j = 0; j < 4; j++) pk[j] = f2bf(vv[j]);
        *(u16x4*)(outb + ((size_t)(bb*512 + colg)) * 2048 + ss) = pk;
      } else {                                          // OUTM 3: fused k|v
        if (n0 < 512){
#pragma unroll
          for (int j = 0; j < 4; j++) outb[(size_t)(rowg + j) * 512 + colg] = f2bf(vv[j]);
        } else {
          const int bb = rowg >> 11, ss = rowg & 2047;
          u16x4 pk;
#pragma unroll
          for (int j = 0; j < 4; j++) pk[j] = f2bf(vv[j]);
          *(u16x4*)(outb2 + ((size_t)(bb*512 + (colg - 512))) * 2048 + ss) = pk;
        }
      }
    }
  }
}

template<int TM, int TN, bool BIAS, bool RES, bool GELU_ACT, int OUTM, bool QSC = false>
__global__ __launch_bounds__(256, 4) void k_gemm(
    const u16* __restrict__ A, const u16* __restrict__ BT,
    const float* __restrict__ bias, const u16* __restrict__ res,
    float* __restrict__ outf, u16* __restrict__ outb, u16* __restrict__ outb2,
    int M, int N, int K)
{
  __shared__ u16 Sb[(TM + TN) * 64];
  gemm_body<TM,TN,BIAS,RES,GELU_ACT,OUTM,QSC>(
      Sb, blockIdx.y * gridDim.x + blockIdx.x, gridDim.x,
      gridDim.x * gridDim.y, A, BT, bias, res, outf, outb, outb2, M, N, K);
}

// fused q-projection (512 blocks) + k|v projection (1024 blocks): independent
// consumers of LN12; one dispatch packs the machine. 24KB dynamic LDS shared.
__global__ __launch_bounds__(256, 4) void k_gemm_qkv(
    const u16* __restrict__ xnB, const u16* __restrict__ WqT, u16* __restrict__ qB,
    const u16* __restrict__ ynB, const u16* __restrict__ WkT,
    u16* __restrict__ kB, u16* __restrict__ vtB)
{
  extern __shared__ u16 Sb[];
  const int bid = blockIdx.x;
  if (bid < 512){
    gemm_body<64,128,false,false,false,1,true>(
        Sb, bid, 4, 512, xnB, WqT, nullptr, nullptr, nullptr, qB, nullptr,
        8192, 512, 512);
  } else {
    gemm_body<64,128,false,false,false,3,false>(
        Sb, bid - 512, 8, 1024, ynB, WkT, nullptr, nullptr, nullptr, kB, vtB,
        8192, 1024, 768);
  }
}

// ---------------- flash cross-attention v8: KVBLK=128, 48KB LDS -------------
// q pre-scaled by 0.125*log2e -> p = exp2(s). no-max softmax (tiny scores).
// K single-buffered (QK reads fenced by barrier B before restage); V double-
// buffered (staged right after barrier A). Softmax interleaved with PV MFMAs.
__global__ __launch_bounds__(256, 3) void k_flash(
    const u16* __restrict__ q, const u16* __restrict__ k,
    const u16* __restrict__ vt, u16* __restrict__ ctx)
{
  __shared__ u16 Kb[128 * 64];         // [key 128][d 64], 128B rows, swizzled
  __shared__ u16 Vb[2][64 * 128];      // [d 64][key 128], 256B rows, swizzled
  const int t = threadIdx.x;
  const int wave = t >> 6, lane = t & 63;
  const int l31 = lane & 31, hi = lane >> 5;
  const int id = blockIdx.y * 16 + blockIdx.x;   // bh*16 + qb
  const int swz = xcd_swizzle(id, 512);
  const int qb = swz & 15, bh = swz >> 4;
  const int b = bh >> 3, h = bh & 7;
  const int qrow0 = qb*128 + wave*32;

  // Q B-frags: qf[ds] = Q[qrow0+l31][h*64 + ds*16 + hi*8 .. +7]
  bf8 qf[4];
  {
    const u16* qp = q + ((size_t)(b*2048 + qrow0 + l31)) * 512 + h*64 + hi*8;
    qf[0] = *(const bf8*)qp;
    qf[1] = *(const bf8*)(qp + 16);
    qf[2] = *(const bf8*)(qp + 32);
    qf[3] = *(const bf8*)(qp + 48);
  }

  // K staging: 8 rows x 128B per gload, pre-swizzled source col
  const int lrow8 = lane >> 3;
  const int csK = (((lane & 7) ^ lrow8) << 3);
  const u16* kgl = k + ((size_t)(b*2048 + lrow8)) * 512 + h*64 + csK;
  // V staging: 4 rows x 256B per gload; swizzle parity depends on slice
  const int lrow4 = lane >> 4;
  const int csVe = (((lane & 15) ^ lrow4) << 3);        // slice%2==0: row&7 = lrow4
  const int csVo = (((lane & 15) ^ (4 + lrow4)) << 3);  // slice%2==1: row&7 = 4+lrow4
  const u16* vrow = vt + ((size_t)(b*512 + h*64 + lrow4)) * 2048;

  f32x16 o0, o1;
#pragma unroll
  for (int r = 0; r < 16; r++){ o0[r] = 0.f; o1[r] = 0.f; }
  float rl = 0.f;

  // prologue: stage tile 0 (K -> Kb, V -> Vb[0])
#pragma unroll
  for (int i = 0; i < 4; i++){
    const int rb = (i*4 + wave) * 8;
    gload16(kgl + (size_t)rb * 512, &Kb[rb * 64]);
    const int sl = i*4 + wave;
    gload16(vrow + (size_t)(sl*4) * 2048 + ((sl & 1) ? csVo : csVe), &Vb[0][sl * 512]);
  }

  int cur = 0;
  for (int it = 0; it < 16; it++){
    asm volatile("s_waitcnt vmcnt(0)" ::: "memory");
    __syncthreads();                       // A: K = tile it, V[cur] = tile it
    if (it + 1 < 16){                      // stage V(it+1) early (V[cur^1] free)
      const int kt = (it + 1) << 7;
#pragma unroll
      for (int i = 0; i < 4; i++){
        const int sl = i*4 + wave;
        gload16(vrow + (size_t)(sl*4) * 2048 + kt + ((sl & 1) ? csVo : csVe),
                &Vb[cur^1][sl * 512]);
      }
    }
    const char* kbuf = (const char*)Kb;
    const char* vbuf = (const char*)Vb[cur];
    // QK^T swapped, 32x32x16: s{krf} covers keys krf*32..+31 for q=l31
    f32x16 s0, s1, s2, s3;
#pragma unroll
    for (int r = 0; r < 16; r++){ s0[r] = 0.f; s1[r] = 0.f; s2[r] = 0.f; s3[r] = 0.f; }
    __builtin_amdgcn_s_setprio(1);
#pragma unroll
    for (int ds = 0; ds < 4; ds++){
      const int off = ds*32 + hi*16;
      const int r0 = l31, r1 = 32 + l31, r2 = 64 + l31, r3 = 96 + l31;
      const bf8 k0 = *(const bf8*)(kbuf + r0*128 + (off ^ ((r0 & 7) << 4)));
      const bf8 k1 = *(const bf8*)(kbuf + r1*128 + (off ^ ((r1 & 7) << 4)));
      const bf8 k2 = *(const bf8*)(kbuf + r2*128 + (off ^ ((r2 & 7) << 4)));
      const bf8 k3 = *(const bf8*)(kbuf + r3*128 + (off ^ ((r3 & 7) << 4)));
      s0 = __builtin_amdgcn_mfma_f32_32x32x16_bf16(k0, qf[ds], s0, 0, 0, 0);
      s1 = __builtin_amdgcn_mfma_f32_32x32x16_bf16(k1, qf[ds], s1, 0, 0, 0);
      s2 = __builtin_amdgcn_mfma_f32_32x32x16_bf16(k2, qf[ds], s2, 0, 0, 0);
      s3 = __builtin_amdgcn_mfma_f32_32x32x16_bf16(k3, qf[ds], s3, 0, 0, 0);
    }
    __builtin_amdgcn_s_setprio(0);
    __syncthreads();                       // B: all QK reads of Kb done
    if (it + 1 < 16){                      // restage K (async, lands by next A)
      const int kt = (it + 1) << 7;
#pragma unroll
      for (int i = 0; i < 4; i++){
        const int rb = (i*4 + wave) * 8;
        gload16(kgl + (size_t)(kt + rb) * 512, &Kb[rb * 64]);
      }
    }
    // softmax (no max-shift) + pack, interleaved with PV per 32-key sub-tile
    float rsum = 0.f;
#define SMPV(SV, SUB)                                                          \
    {                                                                          \
      float pp[16];                                                            \
      _Pragma("unroll")                                                        \
      for (int r = 0; r < 16; r++) pp[r] = __builtin_amdgcn_exp2f(SV[r]);      \
      _Pragma("unroll")                                                        \
      for (int r = 0; r < 16; r++) rsum += pp[r];                              \
      unsigned w0 = cvtpk(pp[0],  pp[1]),  w1 = cvtpk(pp[2],  pp[3]);          \
      unsigned w2 = cvtpk(pp[4],  pp[5]),  w3 = cvtpk(pp[6],  pp[7]);          \
      unsigned w4 = cvtpk(pp[8],  pp[9]),  w5 = cvtpk(pp[10], pp[11]);         \
      unsigned w6 = cvtpk(pp[12], pp[13]), w7 = cvtpk(pp[14], pp[15]);         \
      plswap(w0, w2); plswap(w1, w3);                                          \
      plswap(w4, w6); plswap(w5, w7);                                          \
      u32x4 t0 = {w0, w1, w2, w3};                                             \
      u32x4 t1 = {w4, w5, w6, w7};                                             \
      bf8 pa0, pa1;                                                            \
      __builtin_memcpy(&pa0, &t0, 16);                                         \
      __builtin_memcpy(&pa1, &t1, 16);                                         \
      const int off0 = SUB*64 + hi*16;                                         \
      const int off1 = SUB*64 + 32 + hi*16;                                    \
      const int r0 = l31, r1 = 32 + l31;                                       \
      const bf8 va0 = *(const bf8*)(vbuf + r0*256 + (off0 ^ ((r0 & 7) << 4))); \
      const bf8 va1 = *(const bf8*)(vbuf + r1*256 + (off0 ^ ((r1 & 7) << 4))); \
      const bf8 vb0 = *(const bf8*)(vbuf + r0*256 + (off1 ^ ((r0 & 7) << 4))); \
      const bf8 vb1 = *(const bf8*)(vbuf + r1*256 + (off1 ^ ((r1 & 7) << 4))); \
      o0 = __builtin_amdgcn_mfma_f32_32x32x16_bf16(pa0, va0, o0, 0, 0, 0);     \
      o1 = __builtin_amdgcn_mfma_f32_32x32x16_bf16(pa0, va1, o1, 0, 0, 0);     \
      o0 = __builtin_amdgcn_mfma_f32_32x32x16_bf16(pa1, vb0, o0, 0, 0, 0);     \
      o1 = __builtin_amdgcn_mfma_f32_32x32x16_bf16(pa1, vb1, o1, 0, 0, 0);     \
    }
    SMPV(s0, 0)
    SMPV(s1, 1)
    SMPV(s2, 2)
    SMPV(s3, 3)
#undef SMPV
    rsum += __shfl_xor(rsum, 32);
    rl += rsum;
    cur ^= 1;
  }
  // epilogue: divide by row sum, write ctx. o reg r: q = (r&3)+8*(r>>2)+4*hi,
  // d = dfrag*32 + l31.
  const float linv = 1.f / rl;             // valid for q = l31
#pragma unroll
  for (int r = 0; r < 16; r++){
    const int crow = (r & 3) + 8*(r >> 2) + 4*hi;
    const float iv = __shfl(linv, crow);
    u16* cp = ctx + ((size_t)(b*2048 + qrow0 + crow)) * 512 + h*64 + l31;
    cp[0]  = f2bf(o0[r] * iv);
    cp[32] = f2bf(o1[r] * iv);
  }
}

// ---------------- tiny MHA (batch_first=False: attends over L=4) ------------
__global__ __launch_bounds__(256) void k_mha_small(const u16* __restrict__ qkv,
                                                   u16* __restrict__ outb)
{
  const int tid = blockIdx.x * 256 + threadIdx.x;  // 65536 threads
  const int n = tid & 2047;
  const int hl = tid >> 11;
  const int h = hl >> 2, l = hl & 3;
  const u16* qp = qkv + ((size_t)l * 2048 + n) * 1536 + h*64;
  float qv[64];
#pragma unroll
  for (int i = 0; i < 8; i++){
    const bf8 c = *(const bf8*)(qp + i*8);
#pragma unroll
    for (int j2 = 0; j2 < 8; j2++) qv[i*8 + j2] = bf2f((u16)c[j2]) * 0.125f;
  }
  float sc[4];
#pragma unroll
  for (int m = 0; m < 4; m++){
    const u16* kp = qkv + ((size_t)m * 2048 + n) * 1536 + 512 + h*64;
    float a = 0.f;
#pragma unroll
    for (int i = 0; i < 8; i++){
      const bf8 c = *(const bf8*)(kp + i*8);
#pragma unroll
      for (int j2 = 0; j2 < 8; j2++) a += qv[i*8 + j2] * bf2f((u16)c[j2]);
    }
    sc[m] = a;
  }
  const float mx = fmaxf(fmaxf(sc[0], sc[1]), fmaxf(sc[2], sc[3]));
  float p[4]; float sum = 0.f;
#pragma unroll
  for (int m = 0; m < 4; m++){ p[m] = __expf(sc[m] - mx); sum += p[m]; }
  const float inv = 1.f / sum;
  float ov[64];
#pragma unroll
  for (int i = 0; i < 64; i++) ov[i] = 0.f;
#pragma unroll
  for (int m = 0; m < 4; m++){
    const float pw = p[m] * inv;
    const u16* vp = qkv + ((size_t)m * 2048 + n) * 1536 + 1024 + h*64;
#pragma unroll
    for (int i = 0; i < 8; i++){
      const bf8 c = *(const bf8*)(vp + i*8);
#pragma unroll
      for (int j2 = 0; j2 < 8; j2++) ov[i*8 + j2] += pw * bf2f((u16)c[j2]);
    }
  }
  u16* op = outb + ((size_t)l * 2048 + n) * 512 + h*64;
#pragma unroll
  for (int i = 0; i < 8; i++){
    u16x8 pk;
#pragma unroll
    for (int j2 = 0; j2 < 8; j2++) pk[j2] = f2bf(ov[i*8 + j2]);
    *(u16x8*)(op + i*8) = pk;
  }
}

// ---------------------------------------------------------------------------
extern "C" void kernel_launch(void* const* d_in, const int* in_sizes, int n_in,
                              void* d_out, int out_size, void* d_ws, size_t ws_size,
                              hipStream_t stream)
{
  (void)in_sizes; (void)n_in; (void)out_size; (void)ws_size;
  const float* x    = (const float*)d_in[0];
  const float* y    = (const float*)d_in[1];
  const float* Wq   = (const float*)d_in[2];
  const float* Wk   = (const float*)d_in[3];
  const float* Wv   = (const float*)d_in[4];
  const float* Wo   = (const float*)d_in[5];
  const float* bo   = (const float*)d_in[6];
  const float* Win  = (const float*)d_in[7];
  const float* bin  = (const float*)d_in[8];
  const float* Wmo  = (const float*)d_in[9];
  const float* bmo  = (const float*)d_in[10];
  const float* ln1g = (const float*)d_in[11];
  const float* ln1b = (const float*)d_in[12];
  const float* ln2g = (const float*)d_in[13];
  const float* ln2b = (const float*)d_in[14];
  const float* ln3g = (const float*)d_in[15];
  const float* ln3b = (const float*)d_in[16];
  const float* ln4g = (const float*)d_in[17];
  const float* ln4b = (const float*)d_in[18];
  const float* W1   = (const float*)d_in[19];
  const float* b1   = (const float*)d_in[20];
  const float* W2   = (const float*)d_in[21];
  const float* b2   = (const float*)d_in[22];

  char* ws = (char*)d_ws;
  const size_t MB = 1024 * 1024;
  // bf16 transposed weights (~8.5 MB); WkT and WvT adjacent -> fused k|v GEMM
  u16* WqT  = (u16*)ws;
  u16* WkT  = WqT  + 512 * 512;
  u16* WvT  = WkT  + 512 * 768;
  u16* WoT  = WvT  + 512 * 768;
  u16* WinT = WoT  + 512 * 512;
  u16* WmoT = WinT + 1536 * 512;
  u16* W1T  = WmoT + 512 * 512;
  u16* W2T  = W1T  + 2048 * 512;
  // all-bf16 activation buffers with lifetime-based aliasing (<=109 MB)
  u16* xnB  = (u16*)(ws +   9 * MB);  // 8MB  LN1 out; res for Wo
  u16* ynB  = (u16*)(ws +  17 * MB);  // 12MB LN2 out
  u16* qB   = (u16*)(ws +  29 * MB);  // 8MB  q (pre-scaled); dead after flash
  u16* kB   = (u16*)(ws +  37 * MB);  // 8MB  k; dead after flash
  u16* vtB  = (u16*)(ws +  45 * MB);  // 8MB  v^T; dead after flash
  u16* ctxB = (u16*)(ws +  53 * MB);  // 8MB  flash out; dead after Wo
  u16* carB = (u16*)(ws +  61 * MB);  // 8MB  ca+xn; dead after LN3
  u16* hB   = (u16*)(ws +  69 * MB);  // 8MB  LN3 out; res for Wmo
  u16* qkvB = (u16*)(ws +  77 * MB);  // 24MB Win out; dead after mha
  u16* saB  = (u16*)(ws + 101 * MB);  // 8MB  mha out
  u16* sarB = qB;                     // sa+h (qB dead)
  u16* h2B  = kB;                     // LN4 out (kB dead)
  u16* t1B  = vtB;                    // 32MB GELU(..) spans 45..77 (all dead)

  // fused LN1+LN2+weight transposes (independent work, one dispatch)
  k_prologue<<<20736, 256, 0, stream>>>(
      x, y, ln1g, ln1b, ln2g, ln2b, xnB, ynB,
      Wq, Wk, Wv, Wo, Win, Wmo, W1, W2,
      WqT, WkT, WvT, WoT, WinT, WmoT, W1T, W2T);

  // fused q-projection + k|v projection (independent, one dispatch)
  k_gemm_qkv<<<1536, 256, 24576, stream>>>(xnB, WqT, qB, ynB, WkT, kB, vtB);

  k_flash<<<dim3(16, 32), 256, 0, stream>>>(qB, kB, vtB, ctxB);

  // car = ctx@Wo + bo + xn (bf16) -> LN3 -> h (bf16)
  k_gemm<64,128,true,true,false,1><<<dim3(4, 128), 256, 0, stream>>>(ctxB, WoT, bo, xnB, nullptr, carB, nullptr, 8192, 512, 512);
  k_layernorm_b<<<8192, 256, 0, stream>>>(carB, ln3g, ln3b, hB);

  // MHA over L=4: in-proj (128x128), tiny attention, out-proj -> LN4 -> h2
  k_gemm<128,128,true,false,false,1><<<dim3(12, 64), 256, 0, stream>>>(hB, WinT, bin, nullptr, nullptr, qkvB, nullptr, 8192, 1536, 512);
  k_mha_small<<<256, 256, 0, stream>>>(qkvB, saB);
  k_gemm<64,128,true,true,false,1><<<dim3(4, 128), 256, 0, stream>>>(saB, WmoT, bmo, hB, nullptr, sarB, nullptr, 8192, 512, 512);
  k_layernorm_b<<<8192, 256, 0, stream>>>(sarB, ln4g, ln4b, h2B);

  // MLP: GELU(h2@W1 + b1) at 128x128; W2 + residual -> d_out (f32)
  k_gemm<128,128,true,false,true,1><<<dim3(16, 64), 256, 0, stream>>>(h2B, W1T, b1, nullptr, nullptr, t1B, nullptr, 8192, 2048, 512);
  k_gemm<64,128,true,true,false,0><<<dim3(4, 128), 256, 0, stream>>>(t1B, W2T, b2, h2B, (float*)d_out, nullptr, nullptr, 8192, 512, 2048);
}